// Round 13
// baseline (327.875 us; speedup 1.0000x reference)
//
#include <hip/hip_runtime.h>

// MultiheadAtt: B=4, S=2048, D=512, H=8, HD=64.  M = B*S = 8192 tokens.
// .view() reshape is a raw row-major no-op: chunk c = m>>8, l = (m&255)*8 +
// (n>>6), hd = n&63; flat [m][n] == [c][l][hd] (32 chunks x 2048 x 64).
// Outputs: out (8192*512 f32) then probs (32*2048*2048 f32).
//
// Round 13: R12's probs-only failure isolates to the pass-2 sPf LDS overlay
// (out passed => pass 1 / rsum / staging / 8-wave geometry all proven).
// Pass 2 rebuilt with NO LDS: swapped-operand MFMA  s = mfma(K_frag, Q_frag)
// gives lane (g,l15) reg r the value S[q=l15][k=cb*16+g*4+r] -- 4 consecutive
// k per lane -> direct global_store_dwordx4 from registers. 1/rowsum for
// q=l15 redistributed once via 4 const-indexed __shfl + cndmask.
// Pass 1 byte-identical to R12. LDS 35840 B (4 blocks/CU).

typedef __attribute__((ext_vector_type(4))) float fvec4;
typedef __attribute__((ext_vector_type(4))) float f32x4;
typedef __attribute__((ext_vector_type(8))) short bf16x8;
typedef __attribute__((ext_vector_type(4))) short bf16x4;

typedef const __attribute__((address_space(1))) unsigned int* gas_t;
typedef __attribute__((address_space(3))) unsigned int* las_t;

__device__ inline void gl_lds16(const void* g, void* l) {
    __builtin_amdgcn_global_load_lds((gas_t)g, (las_t)l, 16, 0, 0);
}

__device__ inline unsigned short f2bf_rne(float x) {
    unsigned u = __builtin_bit_cast(unsigned, x);
    unsigned r = (u + 0x7FFFu + ((u >> 16) & 1u)) >> 16;
    return (unsigned short)r;
}
__device__ inline float bf2f(unsigned short h) {
    unsigned u = ((unsigned)h) << 16;
    return __builtin_bit_cast(float, u);
}

// swizzled LDS frag offset (shorts), 32-short rows: 4 chunks, XOR (row>>1)&3
__device__ inline int fo4(int row, int ch) { return row * 32 + ((ch ^ ((row >> 1) & 3)) * 8); }

// ---------------------------------------------------- prep: f32 -> bf16 (hi)
__global__ __launch_bounds__(256) void split3h(
    const float* __restrict__ X0, const float* __restrict__ X1, const float* __restrict__ X2,
    unsigned short* __restrict__ Hb)
{
    const float* X = blockIdx.z == 0 ? X0 : blockIdx.z == 1 ? X1 : X2;
    unsigned short* H = Hb + (long long)blockIdx.z * 4194304;
    const long long i = (long long)(blockIdx.x * 256 + threadIdx.x) * 8;
    fvec4 a = *(const fvec4*)(X + i);
    fvec4 b = *(const fvec4*)(X + i + 4);
    bf16x8 h;
#pragma unroll
    for (int j = 0; j < 4; j++) {
        h[j]     = (short)f2bf_rne(a[j]);
        h[4 + j] = (short)f2bf_rne(b[j]);
    }
    *(bf16x8*)(H + i) = h;
}

// --------------------------------------- weight transpose + split to bf16 hi/lo
__global__ __launch_bounds__(256) void wtrans_split(
    const float* __restrict__ W0, const float* __restrict__ W1,
    const float* __restrict__ W2, const float* __restrict__ W3,
    unsigned short* __restrict__ TH, unsigned short* __restrict__ TL)
{
    const float* W = blockIdx.z == 0 ? W0 : blockIdx.z == 1 ? W1 : blockIdx.z == 2 ? W2 : W3;
    unsigned short* th = TH + (long long)blockIdx.z * 262144;
    unsigned short* tl = TL + (long long)blockIdx.z * 262144;
    __shared__ float t[32][33];
    const int x = threadIdx.x, y = threadIdx.y;  // block (32,8)
    const int n0 = blockIdx.x * 32, k0 = blockIdx.y * 32;
#pragma unroll
    for (int j = 0; j < 4; j++) t[y + 8 * j][x] = W[(long long)(k0 + y + 8 * j) * 512 + n0 + x];
    __syncthreads();
#pragma unroll
    for (int j = 0; j < 4; j++) {
        float v = t[x][y + 8 * j];
        unsigned short h = f2bf_rne(v);
        th[(long long)(n0 + y + 8 * j) * 512 + k0 + x] = h;
        tl[(long long)(n0 + y + 8 * j) * 512 + k0 + x] = f2bf_rne(v - bf2f(h));
    }
}

// ------------------------------------ 2-term split GEMM, 128x128 tile, dbuf LDS
// C[8192][512] = A @ Bt^T + bias, A plain bf16, Bt split hi/lo bf16.
template <bool SPLIT_OUT>
__global__ __launch_bounds__(256) void gemm_2t(
    const unsigned short* __restrict__ AH, long long sAz,
    const unsigned short* __restrict__ BH, const unsigned short* __restrict__ BL, long long sBz,
    const float* __restrict__ b0, const float* __restrict__ b1, const float* __restrict__ b2,
    unsigned short* __restrict__ OH, float* __restrict__ OF, long long sOz)
{
    __shared__ __align__(16) unsigned short sAh[2][4096];
    __shared__ __align__(16) unsigned short sBh[2][4096];
    __shared__ __align__(16) unsigned short sBl[2][4096];

    const int tid = threadIdx.x, lane = tid & 63, wv = tid >> 6;
    const int z = blockIdx.z;
    AH += z * sAz; BH += z * sBz; BL += z * sBz;
    const float* bias = z == 0 ? b0 : z == 1 ? b1 : b2;
    const int row0 = blockIdx.x * 128, col0 = blockIdx.y * 128;
    const int wr = wv >> 1, wc = wv & 1;
    const int l15 = lane & 15, g = lane >> 4;

    const unsigned short* srcA  = AH + (long long)row0 * 512;
    const unsigned short* srcBh = BH + (long long)col0 * 512;
    const unsigned short* srcBl = BL + (long long)col0 * 512;
    const int srow = lane >> 2;                       // row within 16-row group
    const int csrc = (lane & 3) ^ ((lane >> 3) & 3);  // inverse of fo4 swizzle

    f32x4 acc[4][4];
#pragma unroll
    for (int a = 0; a < 4; a++)
#pragma unroll
        for (int b = 0; b < 4; b++)
#pragma unroll
            for (int r = 0; r < 4; r++) acc[a][b][r] = 0.f;

    auto stage = [&](int buf, int k0) {
#pragma unroll
        for (int e = 0; e < 6; e++) {
            const int idx = wv * 6 + e;       // 0..23
            const int t = idx >> 3, i = idx & 7;
            const unsigned short* s_ = t == 0 ? srcA : t == 1 ? srcBh : srcBl;
            unsigned short* d_ = t == 0 ? &sAh[0][0] : t == 1 ? &sBh[0][0] : &sBl[0][0];
            gl_lds16(s_ + (long long)(i * 16 + srow) * 512 + k0 + csrc * 8,
                     d_ + buf * 4096 + i * 512);
        }
    };

    stage(0, 0);
    __syncthreads();
    int cur = 0;
    for (int t = 0; t < 16; t++) {
        if (t < 15) stage(cur ^ 1, (t + 1) * 32);
        bf16x8 aHf[4];
#pragma unroll
        for (int rb = 0; rb < 4; rb++) {
            const int r = wr * 64 + rb * 16 + l15;
            aHf[rb] = *(const bf16x8*)&sAh[cur][fo4(r, g)];
        }
#pragma unroll
        for (int cb = 0; cb < 4; cb++) {
            const int rB = wc * 64 + cb * 16 + l15;
            bf16x8 bH = *(const bf16x8*)&sBh[cur][fo4(rB, g)];
            bf16x8 bL = *(const bf16x8*)&sBl[cur][fo4(rB, g)];
#pragma unroll
            for (int rb = 0; rb < 4; rb++) {
                acc[rb][cb] = __builtin_amdgcn_mfma_f32_16x16x32_bf16(aHf[rb], bH, acc[rb][cb], 0, 0, 0);
                acc[rb][cb] = __builtin_amdgcn_mfma_f32_16x16x32_bf16(aHf[rb], bL, acc[rb][cb], 0, 0, 0);
            }
        }
        __syncthreads();
        cur ^= 1;
    }

#pragma unroll
    for (int rb = 0; rb < 4; rb++) {
#pragma unroll
        for (int cb = 0; cb < 4; cb++) {
            const int col = col0 + wc * 64 + cb * 16 + l15;
#pragma unroll
            for (int rr = 0; rr < 4; rr++) {
                const long long row = row0 + wr * 64 + rb * 16 + g * 4 + rr;
                float val = acc[rb][cb][rr] + bias[col];
                if constexpr (SPLIT_OUT) {
                    (OH + z * sOz)[row * 512 + col] = f2bf_rne(val);
                } else {
                    (OF + z * sOz)[row * 512 + col] = val;
                }
            }
        }
    }
}

// ----------------------------------------------- v transpose: vt[c][hd][l] bf16
__global__ __launch_bounds__(256) void vtrans2(
    const unsigned short* __restrict__ vh, unsigned short* __restrict__ vt)
{
    __shared__ __align__(16) unsigned short t[64][80];
    const int tid = threadIdx.x;
    const int c = blockIdx.y;
    const int l0 = blockIdx.x * 64;
    const long long cb = (long long)c * 131072;
    const int rrow = tid >> 3, ccol = (tid & 7) * 8;
#pragma unroll
    for (int rr = 0; rr < 2; rr++)
        *(bf16x8*)&t[rrow + rr * 32][ccol] =
            *(const bf16x8*)(vh + cb + (long long)(l0 + rrow + rr * 32) * 64 + ccol);
    __syncthreads();
#pragma unroll
    for (int rr = 0; rr < 2; rr++) {
        const int hd = rrow + rr * 32;
        bf16x8 o;
#pragma unroll
        for (int q2 = 0; q2 < 8; q2++) o[q2] = (short)t[ccol + q2][hd];
        *(bf16x8*)(vt + cb + (long long)hd * 2048 + l0 + ccol) = o;
    }
}

// --------------------------------------- fused scores + softmax + PV + probs
// 8 waves / 128 q-rows per block. Pass 1 as R12 (proven by Output 0).
// Pass 2: swapped MFMA, register-direct dwordx4 probs stores, no LDS reuse.
__global__ __launch_bounds__(512) void fused_attn(
    const unsigned short* __restrict__ qh, const unsigned short* __restrict__ kh,
    const unsigned short* __restrict__ vt,
    float* __restrict__ probs, unsigned short* __restrict__ aoh)
{
    // smem: skh [64][72] sh @0 (9216) | svt [64][72] sh @9216 | sP [8][16][68] sh @18432
    __shared__ __align__(16) char smem[35840];
    unsigned short (*skh)[72] = (unsigned short(*)[72])smem;
    unsigned short (*svt)[72] = (unsigned short(*)[72])(smem + 9216);
    unsigned short (*sP)[16][68] = (unsigned short(*)[16][68])(smem + 18432);

    const int tid = threadIdx.x, lane = tid & 63, wv = tid >> 6;  // wv 0..7

    // XCD-bijective swizzle: 512 blocks = 8 XCDs x 64; 4 chunks per XCD.
    const int orig = blockIdx.y * 16 + blockIdx.x;
    const int myid = (orig & 7) * 64 + (orig >> 3);
    const int c    = myid >> 4;
    const int row0 = (myid & 15) * 128;
    const long long cbase = (long long)c * 131072;

    const int l15 = lane & 15, g = lane >> 4, kk = g * 8;
    const int srow = tid >> 3;          // staging row 0..63
    const int scol = (tid & 7) * 8;     // staging col chunk
    const int p_r0 = g * 4;

    // Q fragments (held whole kernel)
    const int arow = row0 + wv * 16 + l15;
    bf16x8 aH[2];
    {
        const unsigned short* qp = qh + cbase + (long long)arow * 64;
        aH[0] = *(const bf16x8*)(qp + kk);
        aH[1] = *(const bf16x8*)(qp + 32 + kk);
    }

    bf16x8 rkh, rvt_;
    auto ld1 = [&](int j) {
        rkh  = *(const bf16x8*)(kh + cbase + (long long)(j * 64 + srow) * 64 + scol);
        rvt_ = *(const bf16x8*)(vt + cbase + (long long)srow * 2048 + j * 64 + scol);
    };
    auto st1 = [&]() {
        *(bf16x8*)&skh[srow][scol] = rkh;
        *(bf16x8*)&svt[srow][scol] = rvt_;
    };
    auto ld2 = [&](int j) {
        rkh = *(const bf16x8*)(kh + cbase + (long long)(j * 64 + srow) * 64 + scol);
    };
    auto st2 = [&]() {
        *(bf16x8*)&skh[srow][scol] = rkh;
    };

    f32x4 acc_o[4];
#pragma unroll
    for (int i = 0; i < 4; i++)
#pragma unroll
        for (int r = 0; r < 4; r++) acc_o[i][r] = 0.f;
    float rsum[4] = {0.f, 0.f, 0.f, 0.f};

    // ---- pass 1: S, exp, row-sums, PV (unnormalized)
    ld1(0);
    for (int j = 0; j < 32; j++) {
        __syncthreads();   // prior-iter LDS reads done
        st1();
        if (j < 31) ld1(j + 1);
        __syncthreads();

        f32x4 s[4];
#pragma unroll
        for (int cb = 0; cb < 4; cb++)
#pragma unroll
            for (int r = 0; r < 4; r++) s[cb][r] = 0.f;
#pragma unroll
        for (int ks = 0; ks < 2; ks++) {
#pragma unroll
            for (int cb = 0; cb < 4; cb++) {
                bf16x8 bH = *(const bf16x8*)&skh[cb * 16 + l15][ks * 32 + kk];
                s[cb] = __builtin_amdgcn_mfma_f32_16x16x32_bf16(aH[ks], bH, s[cb], 0, 0, 0);
            }
        }
#pragma unroll
        for (int cb = 0; cb < 4; cb++) {
#pragma unroll
            for (int r = 0; r < 4; r++) {
                float p = __expf(s[cb][r] * 0.125f);
                rsum[r] += p;
                sP[wv][p_r0 + r][cb * 16 + l15] = f2bf_rne(p);
            }
        }
        // PV: A-frag from own wave's sP strip (no barrier needed)
#pragma unroll
        for (int ks = 0; ks < 2; ks++) {
            bf16x4 p0 = *(const bf16x4*)&sP[wv][l15][ks * 32 + kk];
            bf16x4 p1 = *(const bf16x4*)&sP[wv][l15][ks * 32 + kk + 4];
            bf16x8 pa;
#pragma unroll
            for (int q2 = 0; q2 < 4; q2++) { pa[q2] = p0[q2]; pa[4 + q2] = p1[q2]; }
#pragma unroll
            for (int co = 0; co < 4; co++) {
                bf16x8 bV = *(const bf16x8*)&svt[co * 16 + l15][ks * 32 + kk];
                acc_o[co] = __builtin_amdgcn_mfma_f32_16x16x32_bf16(pa, bV, acc_o[co], 0, 0, 0);
            }
        }
    }

    // 1/rowsum (reduce across the 16 col-lanes; uniform within each 16-lane group)
#pragma unroll
    for (int r = 0; r < 4; r++) {
        float s = rsum[r];
        s += __shfl_xor(s, 1, 64);
        s += __shfl_xor(s, 2, 64);
        s += __shfl_xor(s, 4, 64);
        s += __shfl_xor(s, 8, 64);
        rsum[r] = 1.f / s;
    }

    // ao epilogue -> bf16 (feeds out-projection)
#pragma unroll
    for (int co = 0; co < 4; co++) {
#pragma unroll
        for (int r = 0; r < 4; r++) {
            const long long oi = cbase + (long long)(row0 + wv * 16 + p_r0 + r) * 64 + co * 16 + l15;
            aoh[oi] = f2bf_rne(acc_o[co][r] * rsum[r]);
        }
    }

    // ---- rsum redistribution for pass 2: rsum_q = 1/sum of q-row l15.
    // rsum[r] on group g' holds row g'*4+r (uniform in-group) -> pull from
    // lane (l15>>2)*16 with constant index r, then cndmask-select r = l15&3.
    const int srcl = (l15 >> 2) << 4;
    float t0 = __shfl(rsum[0], srcl, 64);
    float t1 = __shfl(rsum[1], srcl, 64);
    float t2 = __shfl(rsum[2], srcl, 64);
    float t3 = __shfl(rsum[3], srcl, 64);
    float ta = (l15 & 1) ? t1 : t0;
    float tb = (l15 & 1) ? t3 : t2;
    const float rsum_q = (l15 & 2) ? tb : ta;

    // ---- pass 2: swapped MFMA s = K x Q^T; lane holds S[q=l15][k=cb*16+g*4+r]
    // -> direct dwordx4 stores, no LDS beyond skh staging.
    ld2(0);
    float* pq = probs + (long long)c * 4194304 + (long long)(row0 + wv * 16 + l15) * 2048;
    for (int j = 0; j < 32; j++) {
        __syncthreads();
        st2();
        if (j < 31) ld2(j + 1);
        __syncthreads();

        f32x4 s[4];
#pragma unroll
        for (int cb = 0; cb < 4; cb++)
#pragma unroll
            for (int r = 0; r < 4; r++) s[cb][r] = 0.f;
#pragma unroll
        for (int ks = 0; ks < 2; ks++) {
#pragma unroll
            for (int cb = 0; cb < 4; cb++) {
                bf16x8 bK = *(const bf16x8*)&skh[cb * 16 + l15][ks * 32 + kk];
                s[cb] = __builtin_amdgcn_mfma_f32_16x16x32_bf16(bK, aH[ks], s[cb], 0, 0, 0);
            }
        }
#pragma unroll
        for (int cb = 0; cb < 4; cb++) {
            fvec4 v;
#pragma unroll
            for (int r = 0; r < 4; r++) v[r] = __expf(s[cb][r] * 0.125f) * rsum_q;
            *(fvec4*)(pq + j * 64 + cb * 16 + (g << 2)) = v;
        }
    }
}

extern "C" void kernel_launch(void* const* d_in, const int* in_sizes, int n_in,
                              void* d_out, int out_size, void* d_ws, size_t ws_size,
                              hipStream_t stream)
{
    const float* query = (const float*)d_in[0];
    const float* key_  = (const float*)d_in[1];
    const float* value = (const float*)d_in[2];
    const float* Wq = (const float*)d_in[3];
    const float* bq = (const float*)d_in[4];
    const float* Wk = (const float*)d_in[5];
    const float* bk = (const float*)d_in[6];
    const float* Wv = (const float*)d_in[7];
    const float* bv = (const float*)d_in[8];
    const float* Wo = (const float*)d_in[9];
    const float* bo = (const float*)d_in[10];

    float* out   = (float*)d_out;
    float* probs = out + 4194304LL;

    // d_ws layout (68 MiB total)
    const long long MiB = 1LL << 20;
    char* w = (char*)d_ws;
    unsigned short* QKVH = (unsigned short*)(w + 0 * MiB);   // 24 MiB (qh,kh,vh)
    unsigned short* WTH  = (unsigned short*)(w + 24 * MiB);  // 2 MiB
    unsigned short* WTL  = (unsigned short*)(w + 26 * MiB);  // 2 MiB
    unsigned short* VT   = (unsigned short*)(w + 28 * MiB);  // 8 MiB
    unsigned short* AOH  = (unsigned short*)(w + 36 * MiB);  // 8 MiB
    unsigned short* XH   = (unsigned short*)(w + 44 * MiB);  // 24 MiB (x_q,x_k,x_v hi)

    split3h<<<dim3(2048, 1, 3), 256, 0, stream>>>(query, key_, value, XH);
    wtrans_split<<<dim3(16, 16, 4), dim3(32, 8, 1), 0, stream>>>(Wq, Wk, Wv, Wo, WTH, WTL);

    // q/k/v projections (z = 0,1,2); M = 8192, N = 512 -> grid (64,4,3)
    gemm_2t<true><<<dim3(64, 4, 3), 256, 0, stream>>>(
        XH, 4194304, WTH, WTL, 262144, bq, bk, bv,
        QKVH, nullptr, 4194304);

    vtrans2<<<dim3(32, 32, 1), 256, 0, stream>>>(QKVH + 2 * 4194304LL, VT);

    fused_attn<<<dim3(16, 32, 1), 512, 0, stream>>>(
        QKVH, QKVH + 4194304LL, VT, probs, AOH);

    // out = ao @ Wo + bo; grid (64,4,1)
    gemm_2t<false><<<dim3(64, 4, 1), 256, 0, stream>>>(
        AOH, 0, WTH + 3 * 262144LL, WTL + 3 * 262144LL, 0, bo, bo, bo,
        nullptr, out, 0);
}

// Round 14
// 304.748 us; speedup vs baseline: 1.0759x; 1.0759x over previous
//
#include <hip/hip_runtime.h>

// MultiheadAtt: B=4, S=2048, D=512, H=8, HD=64.  M = B*S = 8192 tokens.
// .view() reshape is a raw row-major no-op: chunk c = m>>8, l = (m&255)*8 +
// (n>>6), hd = n&63; flat [m][n] == [c][l][hd] (32 chunks x 2048 x 64).
// Outputs: out (8192*512 f32) then probs (32*2048*2048 f32).
//
// Round 14 = Round 7 (best: 297.9us) + ONE change: fused_attn pass 2 uses
// swapped-operand MFMA (s^T = Kh*Qh^T + Kl*Qh^T + Kh*Ql^T; proven in R13)
// so lane (g,l15) reg r holds S[q=l15][k=cb*16+g*4+r] -> register-direct
// global_store_dwordx4, replacing 16 scalar stores/lane/j. No LDS overlay,
// no occupancy change. R8-R13's slimmed variants all regressed vs R7
// (3-MFMA/tile + 3-array staging hides the 2-barrier stage latency).

typedef __attribute__((ext_vector_type(4))) float fvec4;
typedef __attribute__((ext_vector_type(4))) float f32x4;
typedef __attribute__((ext_vector_type(8))) short bf16x8;
typedef __attribute__((ext_vector_type(4))) short bf16x4;

typedef const __attribute__((address_space(1))) unsigned int* gas_t;
typedef __attribute__((address_space(3))) unsigned int* las_t;

__device__ inline void gl_lds16(const void* g, void* l) {
    __builtin_amdgcn_global_load_lds((gas_t)g, (las_t)l, 16, 0, 0);
}

__device__ inline unsigned short f2bf_rne(float x) {
    unsigned u = __builtin_bit_cast(unsigned, x);
    unsigned r = (u + 0x7FFFu + ((u >> 16) & 1u)) >> 16;
    return (unsigned short)r;
}
__device__ inline float bf2f(unsigned short h) {
    unsigned u = ((unsigned)h) << 16;
    return __builtin_bit_cast(float, u);
}

// swizzled LDS frag offset (shorts), 32-short rows: 4 chunks, XOR (row>>1)&3
__device__ inline int fo4(int row, int ch) { return row * 32 + ((ch ^ ((row >> 1) & 3)) * 8); }

// ---------------------------------------------------- prep: f32 -> bf16 hi/lo
__global__ __launch_bounds__(256) void split3(
    const float* __restrict__ X0, const float* __restrict__ X1, const float* __restrict__ X2,
    unsigned short* __restrict__ Hb, unsigned short* __restrict__ Lb)
{
    const float* X = blockIdx.z == 0 ? X0 : blockIdx.z == 1 ? X1 : X2;
    unsigned short* H = Hb + (long long)blockIdx.z * 4194304;
    unsigned short* L = Lb + (long long)blockIdx.z * 4194304;
    const long long i = (long long)(blockIdx.x * 256 + threadIdx.x) * 8;
    fvec4 a = *(const fvec4*)(X + i);
    fvec4 b = *(const fvec4*)(X + i + 4);
    bf16x8 h, l;
#pragma unroll
    for (int j = 0; j < 4; j++) {
        unsigned short hh = f2bf_rne(a[j]);
        h[j] = (short)hh; l[j] = (short)f2bf_rne(a[j] - bf2f(hh));
        hh = f2bf_rne(b[j]);
        h[4 + j] = (short)hh; l[4 + j] = (short)f2bf_rne(b[j] - bf2f(hh));
    }
    *(bf16x8*)(H + i) = h;
    *(bf16x8*)(L + i) = l;
}

// --------------------------------------- weight transpose + split to bf16 hi/lo
__global__ __launch_bounds__(256) void wtrans_split(
    const float* __restrict__ W0, const float* __restrict__ W1,
    const float* __restrict__ W2, const float* __restrict__ W3,
    unsigned short* __restrict__ TH, unsigned short* __restrict__ TL)
{
    const float* W = blockIdx.z == 0 ? W0 : blockIdx.z == 1 ? W1 : blockIdx.z == 2 ? W2 : W3;
    unsigned short* th = TH + (long long)blockIdx.z * 262144;
    unsigned short* tl = TL + (long long)blockIdx.z * 262144;
    __shared__ float t[32][33];
    const int x = threadIdx.x, y = threadIdx.y;  // block (32,8)
    const int n0 = blockIdx.x * 32, k0 = blockIdx.y * 32;
#pragma unroll
    for (int j = 0; j < 4; j++) t[y + 8 * j][x] = W[(long long)(k0 + y + 8 * j) * 512 + n0 + x];
    __syncthreads();
#pragma unroll
    for (int j = 0; j < 4; j++) {
        float v = t[x][y + 8 * j];
        unsigned short h = f2bf_rne(v);
        th[(long long)(n0 + y + 8 * j) * 512 + k0 + x] = h;
        tl[(long long)(n0 + y + 8 * j) * 512 + k0 + x] = f2bf_rne(v - bf2f(h));
    }
}

// ------------------------------------------------- split-bf16 GEMM, 128x128 tile
// C[8192][512] = A @ Bt^T + bias. 3-term split MFMA; dbuf global_load_lds.
template <bool SPLIT_OUT>
__global__ __launch_bounds__(256) void gemm_split(
    const unsigned short* __restrict__ AH, const unsigned short* __restrict__ AL, long long sAz,
    const unsigned short* __restrict__ BH, const unsigned short* __restrict__ BL, long long sBz,
    const float* __restrict__ b0, const float* __restrict__ b1, const float* __restrict__ b2,
    unsigned short* __restrict__ OH, unsigned short* __restrict__ OL,
    float* __restrict__ OF, long long sOz)
{
    __shared__ __align__(16) unsigned short sAh[2][4096];
    __shared__ __align__(16) unsigned short sAl[2][4096];
    __shared__ __align__(16) unsigned short sBh[2][4096];
    __shared__ __align__(16) unsigned short sBl[2][4096];

    const int tid = threadIdx.x, lane = tid & 63, wv = tid >> 6;
    const int z = blockIdx.z;
    AH += z * sAz; AL += z * sAz; BH += z * sBz; BL += z * sBz;
    const float* bias = z == 0 ? b0 : z == 1 ? b1 : b2;
    const int row0 = blockIdx.x * 128, col0 = blockIdx.y * 128;
    const int wr = wv >> 1, wc = wv & 1;
    const int l15 = lane & 15, g = lane >> 4;

    const unsigned short* src = wv == 0 ? AH + (long long)row0 * 512
                              : wv == 1 ? AL + (long long)row0 * 512
                              : wv == 2 ? BH + (long long)col0 * 512
                              :           BL + (long long)col0 * 512;
    unsigned short* dst = wv == 0 ? &sAh[0][0] : wv == 1 ? &sAl[0][0]
                        : wv == 2 ? &sBh[0][0] : &sBl[0][0];
    const int srow = lane >> 2;                       // row within 16-row group
    const int csrc = (lane & 3) ^ ((lane >> 3) & 3);  // inverse of fo4 swizzle

    f32x4 acc[4][4];
#pragma unroll
    for (int a = 0; a < 4; a++)
#pragma unroll
        for (int b = 0; b < 4; b++)
#pragma unroll
            for (int r = 0; r < 4; r++) acc[a][b][r] = 0.f;

    auto stage = [&](int buf, int k0) {
#pragma unroll
        for (int i = 0; i < 8; i++) {
            gl_lds16(src + (long long)(i * 16 + srow) * 512 + k0 + csrc * 8,
                     dst + buf * 4096 + i * 512);
        }
    };

    stage(0, 0);
    __syncthreads();
    int cur = 0;
    for (int t = 0; t < 16; t++) {
        if (t < 15) stage(cur ^ 1, (t + 1) * 32);
        bf16x8 aHf[4], aLf[4];
#pragma unroll
        for (int rb = 0; rb < 4; rb++) {
            const int r = wr * 64 + rb * 16 + l15;
            aHf[rb] = *(const bf16x8*)&sAh[cur][fo4(r, g)];
            aLf[rb] = *(const bf16x8*)&sAl[cur][fo4(r, g)];
        }
#pragma unroll
        for (int cb = 0; cb < 4; cb++) {
            const int rB = wc * 64 + cb * 16 + l15;
            bf16x8 bH = *(const bf16x8*)&sBh[cur][fo4(rB, g)];
            bf16x8 bL = *(const bf16x8*)&sBl[cur][fo4(rB, g)];
#pragma unroll
            for (int rb = 0; rb < 4; rb++) {
                acc[rb][cb] = __builtin_amdgcn_mfma_f32_16x16x32_bf16(aHf[rb], bH, acc[rb][cb], 0, 0, 0);
                acc[rb][cb] = __builtin_amdgcn_mfma_f32_16x16x32_bf16(aHf[rb], bL, acc[rb][cb], 0, 0, 0);
                acc[rb][cb] = __builtin_amdgcn_mfma_f32_16x16x32_bf16(aLf[rb], bH, acc[rb][cb], 0, 0, 0);
            }
        }
        __syncthreads();
        cur ^= 1;
    }

#pragma unroll
    for (int rb = 0; rb < 4; rb++) {
#pragma unroll
        for (int cb = 0; cb < 4; cb++) {
            const int col = col0 + wc * 64 + cb * 16 + l15;
#pragma unroll
            for (int rr = 0; rr < 4; rr++) {
                const long long row = row0 + wr * 64 + rb * 16 + g * 4 + rr;
                float val = acc[rb][cb][rr] + bias[col];
                if constexpr (SPLIT_OUT) {
                    unsigned short h = f2bf_rne(val);
                    (OH + z * sOz)[row * 512 + col] = h;
                    if (z != 2)  // v needs hi only
                        (OL + z * sOz)[row * 512 + col] = f2bf_rne(val - bf2f(h));
                } else {
                    (OF + z * sOz)[row * 512 + col] = val;
                }
            }
        }
    }
}

// ----------------------------------------------- v transpose: vt[c][hd][l] bf16
__global__ __launch_bounds__(256) void vtrans2(
    const unsigned short* __restrict__ vh, unsigned short* __restrict__ vt)
{
    __shared__ __align__(16) unsigned short t[64][80];
    const int tid = threadIdx.x;
    const int c = blockIdx.y;
    const int l0 = blockIdx.x * 64;
    const long long cb = (long long)c * 131072;
    const int rrow = tid >> 3, ccol = (tid & 7) * 8;
#pragma unroll
    for (int rr = 0; rr < 2; rr++)
        *(bf16x8*)&t[rrow + rr * 32][ccol] =
            *(const bf16x8*)(vh + cb + (long long)(l0 + rrow + rr * 32) * 64 + ccol);
    __syncthreads();
#pragma unroll
    for (int rr = 0; rr < 2; rr++) {
        const int hd = rrow + rr * 32;
        bf16x8 o;
#pragma unroll
        for (int q2 = 0; q2 < 8; q2++) o[q2] = (short)t[ccol + q2][hd];
        *(bf16x8*)(vt + cb + (long long)hd * 2048 + l0 + ccol) = o;
    }
}

// --------------------------------------- fused scores + softmax + PV + probs
__global__ __launch_bounds__(256) void fused_attn(
    const unsigned short* __restrict__ qh, const unsigned short* __restrict__ ql,
    const unsigned short* __restrict__ kh, const unsigned short* __restrict__ kl,
    const unsigned short* __restrict__ vt,
    float* __restrict__ probs,
    unsigned short* __restrict__ aoh, unsigned short* __restrict__ aol)
{
    __shared__ __align__(16) unsigned short skh[64][80];
    __shared__ __align__(16) unsigned short skl[64][80];
    __shared__ __align__(16) unsigned short svt[64][80];
    __shared__ __align__(16) unsigned short sP[4][16][68];

    const int tid = threadIdx.x, lane = tid & 63, wv = tid >> 6;

    // XCD-bijective swizzle: 1024 blocks = 8 XCDs x 128; each XCD owns 4
    // consecutive chunks -> its K/V set fits the per-XCD 4 MiB L2.
    const int orig = blockIdx.y * 32 + blockIdx.x;
    const int myid = (orig & 7) * 128 + (orig >> 3);
    const int c    = myid >> 5;
    const int row0 = (myid & 31) * 64;
    const long long cbase = (long long)c * 131072;

    const int l15 = lane & 15, g = lane >> 4, kk = g * 8;
    const int srow = tid >> 3;          // staging row 0..31
    const int scol = (tid & 7) * 8;     // staging col chunk
    const int p_r0 = g * 4;

    // ---- Q fragments (held whole kernel)
    const int arow = row0 + wv * 16 + l15;
    bf16x8 aH[2], aL[2];
    {
        const unsigned short* qp  = qh + cbase + (long long)arow * 64;
        const unsigned short* qlp = ql + cbase + (long long)arow * 64;
        aH[0] = *(const bf16x8*)(qp + kk);   aH[1] = *(const bf16x8*)(qp + 32 + kk);
        aL[0] = *(const bf16x8*)(qlp + kk);  aL[1] = *(const bf16x8*)(qlp + 32 + kk);
    }

    bf16x8 rkh[2], rkl[2], rvt[2];
    auto ld1 = [&](int j) {
        const long long ktb = cbase + (long long)j * 4096;
        const long long vtb = cbase + j * 64;
#pragma unroll
        for (int rr = 0; rr < 2; rr++) {
            const int r2 = srow + rr * 32;
            rkh[rr] = *(const bf16x8*)(kh + ktb + (long long)r2 * 64 + scol);
            rkl[rr] = *(const bf16x8*)(kl + ktb + (long long)r2 * 64 + scol);
            rvt[rr] = *(const bf16x8*)(vt + vtb + (long long)r2 * 2048 + scol);
        }
    };
    auto st1 = [&]() {
#pragma unroll
        for (int rr = 0; rr < 2; rr++) {
            const int r2 = srow + rr * 32;
            *(bf16x8*)&skh[r2][scol] = rkh[rr];
            *(bf16x8*)&skl[r2][scol] = rkl[rr];
            *(bf16x8*)&svt[r2][scol] = rvt[rr];
        }
    };
    auto ld2 = [&](int j) {
        const long long ktb = cbase + (long long)j * 4096;
#pragma unroll
        for (int rr = 0; rr < 2; rr++) {
            const int r2 = srow + rr * 32;
            rkh[rr] = *(const bf16x8*)(kh + ktb + (long long)r2 * 64 + scol);
            rkl[rr] = *(const bf16x8*)(kl + ktb + (long long)r2 * 64 + scol);
        }
    };
    auto st2 = [&]() {
#pragma unroll
        for (int rr = 0; rr < 2; rr++) {
            const int r2 = srow + rr * 32;
            *(bf16x8*)&skh[r2][scol] = rkh[rr];
            *(bf16x8*)&skl[r2][scol] = rkl[rr];
        }
    };

    f32x4 acc_o[4];
#pragma unroll
    for (int i = 0; i < 4; i++)
#pragma unroll
        for (int r = 0; r < 4; r++) acc_o[i][r] = 0.f;
    float rsum[4] = {0.f, 0.f, 0.f, 0.f};

    // ---- pass 1: S, exp, row-sums, PV (unnormalized)
    ld1(0);
    for (int j = 0; j < 32; j++) {
        __syncthreads();   // prior-iter LDS reads done
        st1();
        if (j < 31) ld1(j + 1);
        __syncthreads();

        f32x4 s[4];
#pragma unroll
        for (int cb = 0; cb < 4; cb++)
#pragma unroll
            for (int r = 0; r < 4; r++) s[cb][r] = 0.f;
#pragma unroll
        for (int ks = 0; ks < 2; ks++) {
#pragma unroll
            for (int cb = 0; cb < 4; cb++) {
                const int col = cb * 16 + l15;
                bf16x8 bH = *(const bf16x8*)&skh[col][ks * 32 + kk];
                bf16x8 bL = *(const bf16x8*)&skl[col][ks * 32 + kk];
                s[cb] = __builtin_amdgcn_mfma_f32_16x16x32_bf16(aH[ks], bH, s[cb], 0, 0, 0);
                s[cb] = __builtin_amdgcn_mfma_f32_16x16x32_bf16(aH[ks], bL, s[cb], 0, 0, 0);
                s[cb] = __builtin_amdgcn_mfma_f32_16x16x32_bf16(aL[ks], bH, s[cb], 0, 0, 0);
            }
        }
#pragma unroll
        for (int cb = 0; cb < 4; cb++) {
#pragma unroll
            for (int r = 0; r < 4; r++) {
                float p = __expf(s[cb][r] * 0.125f);
                rsum[r] += p;
                sP[wv][p_r0 + r][cb * 16 + l15] = f2bf_rne(p);
            }
        }
        // PV: A-frag from own wave's sP strip (no barrier needed)
#pragma unroll
        for (int ks = 0; ks < 2; ks++) {
            bf16x4 p0 = *(const bf16x4*)&sP[wv][l15][ks * 32 + kk];
            bf16x4 p1 = *(const bf16x4*)&sP[wv][l15][ks * 32 + kk + 4];
            bf16x8 pa;
#pragma unroll
            for (int q2 = 0; q2 < 4; q2++) { pa[q2] = p0[q2]; pa[4 + q2] = p1[q2]; }
#pragma unroll
            for (int co = 0; co < 4; co++) {
                bf16x8 bV = *(const bf16x8*)&svt[co * 16 + l15][ks * 32 + kk];
                acc_o[co] = __builtin_amdgcn_mfma_f32_16x16x32_bf16(pa, bV, acc_o[co], 0, 0, 0);
            }
        }
    }

    // 1/rowsum (reduce across the 16 col-lanes; uniform within 16-lane group)
#pragma unroll
    for (int r = 0; r < 4; r++) {
        float s = rsum[r];
        s += __shfl_xor(s, 1, 64);
        s += __shfl_xor(s, 2, 64);
        s += __shfl_xor(s, 4, 64);
        s += __shfl_xor(s, 8, 64);
        rsum[r] = 1.f / s;
    }

    // ao epilogue -> bf16 hi/lo (feeds out-projection)
#pragma unroll
    for (int co = 0; co < 4; co++) {
#pragma unroll
        for (int r = 0; r < 4; r++) {
            const long long oi = cbase + (long long)(row0 + wv * 16 + p_r0 + r) * 64 + co * 16 + l15;
            float o = acc_o[co][r] * rsum[r];
            unsigned short h = f2bf_rne(o);
            aoh[oi] = h;
            aol[oi] = f2bf_rne(o - bf2f(h));
        }
    }

    // ---- rsum redistribution (R13-proven): rsum_q = 1/sum for q-row l15.
    const int srcl = (l15 >> 2) << 4;
    float t0 = __shfl(rsum[0], srcl, 64);
    float t1 = __shfl(rsum[1], srcl, 64);
    float t2 = __shfl(rsum[2], srcl, 64);
    float t3 = __shfl(rsum[3], srcl, 64);
    float ta = (l15 & 1) ? t1 : t0;
    float tb = (l15 & 1) ? t3 : t2;
    const float rsum_q = (l15 & 2) ? tb : ta;

    // ---- pass 2: swapped MFMA (s^T = Kh*Qh^T + Kl*Qh^T + Kh*Ql^T);
    // lane (g,l15) reg r holds S[q=l15][k=cb*16+g*4+r] -> dwordx4 stores.
    ld2(0);
    float* pq = probs + (long long)c * 4194304 + (long long)(row0 + wv * 16 + l15) * 2048;
    for (int j = 0; j < 32; j++) {
        __syncthreads();
        st2();
        if (j < 31) ld2(j + 1);
        __syncthreads();

        f32x4 s[4];
#pragma unroll
        for (int cb = 0; cb < 4; cb++)
#pragma unroll
            for (int r = 0; r < 4; r++) s[cb][r] = 0.f;
#pragma unroll
        for (int ks = 0; ks < 2; ks++) {
#pragma unroll
            for (int cb = 0; cb < 4; cb++) {
                const int col = cb * 16 + l15;
                bf16x8 bH = *(const bf16x8*)&skh[col][ks * 32 + kk];
                bf16x8 bL = *(const bf16x8*)&skl[col][ks * 32 + kk];
                s[cb] = __builtin_amdgcn_mfma_f32_16x16x32_bf16(bH, aH[ks], s[cb], 0, 0, 0);
                s[cb] = __builtin_amdgcn_mfma_f32_16x16x32_bf16(bL, aH[ks], s[cb], 0, 0, 0);
                s[cb] = __builtin_amdgcn_mfma_f32_16x16x32_bf16(bH, aL[ks], s[cb], 0, 0, 0);
            }
        }
#pragma unroll
        for (int cb = 0; cb < 4; cb++) {
            fvec4 v;
#pragma unroll
            for (int r = 0; r < 4; r++) v[r] = __expf(s[cb][r] * 0.125f) * rsum_q;
            *(fvec4*)(pq + j * 64 + cb * 16 + (g << 2)) = v;
        }
    }
}

extern "C" void kernel_launch(void* const* d_in, const int* in_sizes, int n_in,
                              void* d_out, int out_size, void* d_ws, size_t ws_size,
                              hipStream_t stream)
{
    const float* query = (const float*)d_in[0];
    const float* key_  = (const float*)d_in[1];
    const float* value = (const float*)d_in[2];
    const float* Wq = (const float*)d_in[3];
    const float* bq = (const float*)d_in[4];
    const float* Wk = (const float*)d_in[5];
    const float* bk = (const float*)d_in[6];
    const float* Wv = (const float*)d_in[7];
    const float* bv = (const float*)d_in[8];
    const float* Wo = (const float*)d_in[9];
    const float* bo = (const float*)d_in[10];

    float* out   = (float*)d_out;
    float* probs = out + 4194304LL;

    // Transient input splits in the probs region (dead before probs written).
    unsigned short* XH = (unsigned short*)probs;   // 24 MiB
    unsigned short* XL = XH + 3 * 4194304LL;       // 24 MiB

    // Persistent scratch in d_ws: 68 MiB total.
    const long long MiB = 1LL << 20;
    char* w = (char*)d_ws;
    unsigned short* QKVH = (unsigned short*)(w + 0 * MiB);   // 24 MiB (qh,kh,vh)
    unsigned short* QKVL = (unsigned short*)(w + 24 * MiB);  // 16 MiB (ql,kl)
    unsigned short* WTH  = (unsigned short*)(w + 40 * MiB);  // 2 MiB
    unsigned short* WTL  = (unsigned short*)(w + 42 * MiB);  // 2 MiB
    unsigned short* VT   = (unsigned short*)(w + 44 * MiB);  // 8 MiB
    unsigned short* AOH  = (unsigned short*)(w + 52 * MiB);  // 8 MiB
    unsigned short* AOL  = (unsigned short*)(w + 60 * MiB);  // 8 MiB

    split3<<<dim3(2048, 1, 3), 256, 0, stream>>>(query, key_, value, XH, XL);
    wtrans_split<<<dim3(16, 16, 4), dim3(32, 8, 1), 0, stream>>>(Wq, Wk, Wv, Wo, WTH, WTL);

    // q/k/v projections (z = 0,1,2); M = 8192, N = 512 -> grid (64,4,3)
    gemm_split<true><<<dim3(64, 4, 3), 256, 0, stream>>>(
        XH, XL, 4194304, WTH, WTL, 262144, bq, bk, bv,
        QKVH, QKVL, nullptr, 4194304);

    vtrans2<<<dim3(32, 32, 1), 256, 0, stream>>>(QKVH + 2 * 4194304LL, VT);

    fused_attn<<<dim3(32, 32, 1), 256, 0, stream>>>(
        QKVH, QKVL, QKVH + 4194304LL, QKVL + 4194304LL, VT, probs, AOH, AOL);

    // out = ao @ Wo + bo; grid (64,4,1)
    gemm_split<false><<<dim3(64, 4, 1), 256, 0, stream>>>(
        AOH, AOL, 0, WTH + 3 * 262144LL, WTL + 3 * 262144LL, 0, bo, bo, bo,
        nullptr, nullptr, out, 0);
}